// Round 1
// baseline (10762.310 us; speedup 1.0000x reference)
//
#include <hip/hip_runtime.h>
#include <cstdint>

static __device__ __forceinline__ float leakyf(float v) { return v >= 0.f ? v : 0.2f * v; }

// ------------------------------------------------------------------
// Furthest point sampling (exact, matches jax scan semantics):
// out[0]=0; for it in 1..NP-1: dists=min(dists, d(.,pos[out[it-1]])); out[it]=argmax (first max).
// One block (1024 threads) per batch. Point i owned by thread (i & 1023), slot (i >> 10).
template<int N, int NPOINT>
__global__ __launch_bounds__(1024) void fps_kernel(const float* __restrict__ pos,
                                                   int* __restrict__ out_idx,
                                                   float* __restrict__ out_pos)
{
  constexpr int NPT = N / 1024;
  const int b = blockIdx.x;
  const float* P = pos + (size_t)b * N * 3;
  int* oi = out_idx + (size_t)b * NPOINT;
  float* op = out_pos + (size_t)b * NPOINT * 3;

  __shared__ float sx[N];
  __shared__ float sy[N];
  __shared__ float sz[N];
  __shared__ float red_d[16];
  __shared__ int   red_i[16];
  __shared__ int   s_far;

  const int t = threadIdx.x;
  float px[NPT], py[NPT], pz[NPT], dist[NPT];
#pragma unroll
  for (int j = 0; j < NPT; ++j) {
    int i = t + j * 1024;
    float x = P[i*3+0], y = P[i*3+1], z = P[i*3+2];
    sx[i] = x; sy[i] = y; sz[i] = z;
    px[j] = x; py[j] = y; pz[j] = z;
    dist[j] = 1e10f;
  }
  if (t == 0) oi[0] = 0;
  __syncthreads();

  int far = 0;
  for (int it = 1; it < NPOINT; ++it) {
    const float cx = sx[far], cy = sy[far], cz = sz[far];
    float bd = -1.f; int bi = 0x7fffffff;
#pragma unroll
    for (int j = 0; j < NPT; ++j) {
      float dx = px[j] - cx, dy = py[j] - cy, dz = pz[j] - cz;
      float d = fmaf(dz, dz, fmaf(dy, dy, dx * dx));
      float nd = fminf(dist[j], d);
      dist[j] = nd;
      bool better = nd > bd;
      bd = better ? nd : bd;
      bi = better ? (t + j * 1024) : bi;
    }
    // wave (64-lane) argmax, ties -> lower index
#pragma unroll
    for (int s = 1; s < 64; s <<= 1) {
      float od = __shfl_xor(bd, s);
      int   ob = __shfl_xor(bi, s);
      if (od > bd || (od == bd && ob < bi)) { bd = od; bi = ob; }
    }
    if ((t & 63) == 0) { red_d[t >> 6] = bd; red_i[t >> 6] = bi; }
    __syncthreads();
    if (t < 64) {
      float rd = (t < 16) ? red_d[t] : -1.f;
      int   ri = (t < 16) ? red_i[t] : 0x7fffffff;
#pragma unroll
      for (int s = 1; s < 16; s <<= 1) {
        float od = __shfl_xor(rd, s);
        int   ob = __shfl_xor(ri, s);
        if (od > rd || (od == rd && ob < ri)) { rd = od; ri = ob; }
      }
      if (t == 0) { s_far = ri; oi[it] = ri; }
    }
    __syncthreads();
    far = s_far;
  }
  __syncthreads();
  // gather sampled positions
  for (int i = t; i < NPOINT; i += 1024) {
    int id = oi[i];
    op[i*3+0] = sx[id];
    op[i*3+1] = sy[id];
    op[i*3+2] = sz[id];
  }
}

// ------------------------------------------------------------------
// Self-KNN (K=16) with pairwise formula |a|^2+|b|^2-2ab, stable (d, idx) selection.
// G threads cooperate on one query (interleaved candidate classes), merged via LDS.
template<int G>
__global__ __launch_bounds__(256) void knn_kernel(const float* __restrict__ pos, int M,
                                                  int* __restrict__ out)
{
  const int b = blockIdx.y;
  const float* P = pos + (size_t)b * M * 3;
  const int tid = threadIdx.x;
  constexpr int QPB = 256 / G;
  const int gq = blockIdx.x * QPB + tid / G;
  const int seg = tid % G;

  __shared__ float sx[512], sy[512], sz[512], ss[512];
  __shared__ float md[256 * 16];
  __shared__ int   mi[256 * 16];

  const float qx = P[gq*3+0], qy = P[gq*3+1], qz = P[gq*3+2];
  const float qq = (qx*qx + qy*qy) + qz*qz;

  float a[16]; int id[16];
#pragma unroll
  for (int j = 0; j < 16; ++j) { a[j] = 3.4e38f; id[j] = 0x7fffffff; }

  for (int t0 = 0; t0 < M; t0 += 512) {
    __syncthreads();
    for (int i = tid; i < 512; i += 256) {
      float x = P[(t0+i)*3+0], y = P[(t0+i)*3+1], z = P[(t0+i)*3+2];
      sx[i] = x; sy[i] = y; sz[i] = z;
      ss[i] = (x*x + y*y) + z*z;
    }
    __syncthreads();
    for (int i = seg; i < 512; i += G) {
      float d = (qq + ss[i]) - 2.f * ((qx*sx[i] + qy*sy[i]) + qz*sz[i]);
      int gi = t0 + i;
      if (d < a[15]) {               // insertion into sorted 16-list (stable: ties keep earlier idx)
        bool c[16];
#pragma unroll
        for (int j = 0; j < 16; ++j) c[j] = d < a[j];
#pragma unroll
        for (int j = 15; j >= 1; --j) {
          a[j]  = c[j-1] ? a[j-1]  : (c[j] ? d  : a[j]);
          id[j] = c[j-1] ? id[j-1] : (c[j] ? gi : id[j]);
        }
        if (c[0]) { a[0] = d; id[0] = gi; }
      }
    }
  }
#pragma unroll
  for (int j = 0; j < 16; ++j) { md[tid*16+j] = a[j]; mi[tid*16+j] = id[j]; }
  __syncthreads();
  if (seg == 0) {                    // G-way merge by (d, idx)
    int ptr[G];
#pragma unroll
    for (int g = 0; g < G; ++g) ptr[g] = (tid + g) * 16;
    int* opp = out + ((size_t)b * M + gq) * 16;
    for (int j = 0; j < 16; ++j) {
      float bd = 3.5e38f; int bi = 0x7fffffff; int bg = 0;
#pragma unroll
      for (int g = 0; g < G; ++g) {
        float dd = md[ptr[g]]; int ii = mi[ptr[g]];
        if (dd < bd || (dd == bd && ii < bi)) { bd = dd; bi = ii; bg = g; }
      }
#pragma unroll
      for (int g = 0; g < G; ++g) ptr[g] += (g == bg) ? 1 : 0;
      opp[j] = bi;
    }
  }
}

// ------------------------------------------------------------------
// three_nn + interpolation weights (top-3 by (d, idx), dist clamped >= 0 after selection)
__global__ __launch_bounds__(256) void three_nn_kernel(const float* __restrict__ qpos,
                                                       const float* __restrict__ kpos,
                                                       int Mq, int Mk,
                                                       int* __restrict__ oidx, float* __restrict__ ow)
{
  const int b = blockIdx.y;
  const float* Q  = qpos + (size_t)b * Mq * 3;
  const float* Kp = kpos + (size_t)b * Mk * 3;
  const int qi = blockIdx.x * 256 + threadIdx.x;
  __shared__ float sx[512], sy[512], sz[512], ss[512];
  const float qx = Q[qi*3+0], qy = Q[qi*3+1], qz = Q[qi*3+2];
  const float qq = (qx*qx + qy*qy) + qz*qz;
  float d0 = 3.4e38f, d1 = 3.4e38f, d2 = 3.4e38f;
  int i0 = 0, i1 = 0, i2 = 0;
  for (int t0 = 0; t0 < Mk; t0 += 512) {
    __syncthreads();
    for (int i = threadIdx.x; i < 512; i += 256) {
      float x = Kp[(t0+i)*3+0], y = Kp[(t0+i)*3+1], z = Kp[(t0+i)*3+2];
      sx[i] = x; sy[i] = y; sz[i] = z; ss[i] = (x*x + y*y) + z*z;
    }
    __syncthreads();
    for (int i = 0; i < 512; ++i) {
      float d = (qq + ss[i]) - 2.f * ((qx*sx[i] + qy*sy[i]) + qz*sz[i]);
      int gi = t0 + i;
      if (d < d2) {
        bool c0 = d < d0, c1 = d < d1;
        d2 = c1 ? d1 : d;               i2 = c1 ? i1 : gi;
        d1 = c0 ? d0 : (c1 ? d : d1);   i1 = c0 ? i0 : (c1 ? gi : i1);
        d0 = c0 ? d  : d0;              i0 = c0 ? gi : i0;
      }
    }
  }
  d0 = fmaxf(d0, 0.f); d1 = fmaxf(d1, 0.f); d2 = fmaxf(d2, 0.f);
  float r0 = 1.f/(d0 + 1e-8f), r1 = 1.f/(d1 + 1e-8f), r2 = 1.f/(d2 + 1e-8f);
  float s = (r0 + r1) + r2;
  size_t o = ((size_t)b * Mq + qi) * 3;
  oidx[o+0] = i0; oidx[o+1] = i1; oidx[o+2] = i2;
  ow[o+0] = r0/s; ow[o+1] = r1/s; ow[o+2] = r2/s;
}

// ------------------------------------------------------------------
// Edge-conv neighbor mean: hbar[p] = [mean_k x[n_k], mean_k (pos_p - pos_nk), mean_k |rel|^2]
__global__ void hbar_kernel(const float* __restrict__ x, const float* __restrict__ pos,
                            const int* __restrict__ idx, int Mlvl, int C, int B,
                            float* __restrict__ out)
{
  const int Ct = C + 4;
  const int tot = B * Mlvl * Ct;
  int e = blockIdx.x * 256 + threadIdx.x;
  if (e >= tot) return;
  const int c  = e % Ct;
  const int p  = e / Ct;
  const int b  = p / Mlvl;
  const int lm = p % Mlvl;
  const int* ip = idx + (size_t)p * 16;
  float s = 0.f;
  if (c < C) {
    const float* xb = x + (size_t)b * Mlvl * C;
#pragma unroll 4
    for (int k = 0; k < 16; ++k) s += xb[(size_t)ip[k] * C + c];
  } else if (c < C + 3) {
    const int dd = c - C;
    const float* pb = pos + (size_t)b * Mlvl * 3;
    const float pc = pb[lm*3 + dd];
#pragma unroll 4
    for (int k = 0; k < 16; ++k) s += pc - pb[ip[k]*3 + dd];
  } else {
    const float* pb = pos + (size_t)b * Mlvl * 3;
    const float px = pb[lm*3+0], py = pb[lm*3+1], pz = pb[lm*3+2];
#pragma unroll 4
    for (int k = 0; k < 16; ++k) {
      int n = ip[k];
      float dx = px - pb[n*3+0], dy = py - pb[n*3+1], dz = pz - pb[n*3+2];
      s += (dx*dx + dy*dy) + dz*dz;
    }
  }
  out[e] = s * 0.0625f;
}

// ------------------------------------------------------------------
__global__ void interp_kernel(const float* __restrict__ f, const int* __restrict__ nidx,
                              const float* __restrict__ nw, int Mq, int Msub, int C, int B,
                              float* __restrict__ out)
{
  const int tot = B * Mq * C;
  int e = blockIdx.x * 256 + threadIdx.x;
  if (e >= tot) return;
  const int c = e % C;
  const int p = e / C;
  const int b = p / Mq;
  const float* fb = f + (size_t)b * Msub * C;
  const int* ip   = nidx + (size_t)p * 3;
  const float* wp = nw   + (size_t)p * 3;
  out[e] = (wp[0] * fb[(size_t)ip[0]*C + c] + wp[1] * fb[(size_t)ip[1]*C + c])
         +  wp[2] * fb[(size_t)ip[2]*C + c];
}

// ------------------------------------------------------------------
__global__ void gather_kernel(const float* __restrict__ src, const int* __restrict__ idx,
                              int Mq, int Msrc, int C, int B, float* __restrict__ dst)
{
  const int tot = B * Mq * C;
  int e = blockIdx.x * 256 + threadIdx.x;
  if (e >= tot) return;
  const int c = e % C;
  const int p = e / C;
  const int b = p / Mq;
  dst[e] = src[((size_t)b * Msrc + idx[p]) * C + c];
}

// ------------------------------------------------------------------
// Fused GEMM: out[M,F] = act( A[M,Ka]@W1[Ka,F] + B2[M,Kb]@W2[Kb,F] + bias )
// 64x64 tile, BK=16, 256 threads, 4x4 micro-tile. M,F multiples of 64; K zero-padded.
__global__ __launch_bounds__(256) void gemm_kernel(const float* __restrict__ A, int Ka,
                                                   const float* __restrict__ B2, int Kb,
                                                   const float* __restrict__ W1,
                                                   const float* __restrict__ W2,
                                                   const float* __restrict__ bias,
                                                   float* __restrict__ out,
                                                   int M, int F, int act)
{
  __shared__ __align__(16) float As[16][64];
  __shared__ __align__(16) float Ws[16][64];
  const int tid  = threadIdx.x;
  const int row0 = blockIdx.x * 64;
  const int col0 = blockIdx.y * 64;
  const int tx = tid & 15, ty = tid >> 4;
  const int K = Ka + Kb;
  float acc[4][4] = {};
  for (int k0 = 0; k0 < K; k0 += 16) {
#pragma unroll
    for (int i = 0; i < 4; ++i) {
      int e = tid + i * 256;
      int m = e & 63, kk = e >> 6;
      int k = k0 + kk;
      float v = 0.f;
      if (k < Ka)     v = A [(size_t)(row0 + m) * Ka + k];
      else if (k < K) v = B2[(size_t)(row0 + m) * Kb + (k - Ka)];
      As[kk][m] = v;
      float wv = 0.f;
      if (k < Ka)     wv = W1[(size_t)k * F + col0 + m];
      else if (k < K) wv = W2[(size_t)(k - Ka) * F + col0 + m];
      Ws[kk][m] = wv;
    }
    __syncthreads();
#pragma unroll
    for (int kk = 0; kk < 16; ++kk) {
      const float4 a4 = *reinterpret_cast<const float4*>(&As[kk][ty * 4]);
      const float4 b4 = *reinterpret_cast<const float4*>(&Ws[kk][tx * 4]);
      const float av[4] = {a4.x, a4.y, a4.z, a4.w};
      const float bv[4] = {b4.x, b4.y, b4.z, b4.w};
#pragma unroll
      for (int i2 = 0; i2 < 4; ++i2)
#pragma unroll
        for (int j2 = 0; j2 < 4; ++j2)
          acc[i2][j2] = fmaf(av[i2], bv[j2], acc[i2][j2]);
    }
    __syncthreads();
  }
#pragma unroll
  for (int i2 = 0; i2 < 4; ++i2) {
    int r = row0 + ty * 4 + i2;
#pragma unroll
    for (int j2 = 0; j2 < 4; ++j2) {
      int cc = col0 + tx * 4 + j2;
      float v = acc[i2][j2];
      if (bias) v += bias[cc];
      if (act)  v = leakyf(v);
      out[(size_t)r * F + cc] = v;
    }
  }
}

// ------------------------------------------------------------------
extern "C" void kernel_launch(void* const* d_in, const int* in_sizes, int n_in,
                              void* d_out, int out_size, void* d_ws, size_t ws_size,
                              hipStream_t stream)
{
  (void)in_sizes; (void)n_in; (void)out_size; (void)ws_size;
  const float* x          = (const float*)d_in[0];   // [2,8192,4]
  const float* pos        = (const float*)d_in[1];   // [2,8192,3]
  const float* w_self0    = (const float*)d_in[2];   // [4,64]
  const float* w_edge0    = (const float*)d_in[3];   // [8,64]
  const float* w_self1    = (const float*)d_in[4];   // [64,128]
  const float* w_edge1    = (const float*)d_in[5];   // [68,128]
  const float* w_self2    = (const float*)d_in[6];   // [128,256]
  const float* w_edge2    = (const float*)d_in[7];   // [132,256]
  const float* w_up1      = (const float*)d_in[8];   // [384,128]
  const float* b_up1      = (const float*)d_in[9];   // [128]
  const float* w_upc1s    = (const float*)d_in[10];  // [128,128]
  const float* w_upc1e    = (const float*)d_in[11];  // [132,128]
  const float* w_up0      = (const float*)d_in[12];  // [192,64]
  const float* b_up0      = (const float*)d_in[13];  // [64]
  const float* w_upc0s    = (const float*)d_in[14];  // [64,64]
  const float* w_upc0e    = (const float*)d_in[15];  // [68,64]
  const float* w_out      = (const float*)d_in[16];  // [64,128]
  const float* b_out      = (const float*)d_in[17];  // [128]
  float* out = (float*)d_out;                        // [2,8192,128]

  char* ws = (char*)d_ws;
  size_t off = 0;
  auto alloc = [&](size_t nbytes) -> void* {
    off = (off + 255) & ~(size_t)255;
    void* p = ws + off;
    off += nbytes;
    return p;
  };
  int*   knn0   = (int*)  alloc((size_t)2*8192*16*4);
  int*   knn1   = (int*)  alloc((size_t)2*4096*16*4);
  int*   knn2   = (int*)  alloc((size_t)2*2048*16*4);
  int*   idx1   = (int*)  alloc((size_t)2*4096*4);
  int*   idx2   = (int*)  alloc((size_t)2*2048*4);
  float* pos1   = (float*)alloc((size_t)2*4096*3*4);
  float* pos2   = (float*)alloc((size_t)2*2048*3*4);
  float* feat0  = (float*)alloc((size_t)2*8192*64*4);
  float* feat0g = (float*)alloc((size_t)2*4096*64*4);
  float* feat1  = (float*)alloc((size_t)2*4096*128*4);
  float* feat1g = (float*)alloc((size_t)2*2048*128*4);
  float* feat2  = (float*)alloc((size_t)2*2048*256*4);
  int*   nn1i   = (int*)  alloc((size_t)2*4096*3*4);
  float* nn1w   = (float*)alloc((size_t)2*4096*3*4);
  int*   nn0i   = (int*)  alloc((size_t)2*8192*3*4);
  float* nn0w   = (float*)alloc((size_t)2*8192*3*4);
  float* interp = (float*)alloc((size_t)2*4096*256*4);  // reused for interp0 (same size)
  float* hbar   = (float*)alloc((size_t)2*8192*68*4);   // max of all hbar stages
  float* fupa   = (float*)alloc((size_t)2*4096*128*4);  // fup1a, later fup0a (same size)
  float* fup1   = (float*)alloc((size_t)2*4096*128*4);
  float* fout   = (float*)alloc((size_t)2*8192*64*4);

  // --- level 0: knn + edge conv ---
  knn_kernel<4><<<dim3(128, 2), 256, 0, stream>>>(pos, 8192, knn0);
  hbar_kernel<<<512, 256, 0, stream>>>(x, pos, knn0, 8192, 4, 2, hbar);
  gemm_kernel<<<dim3(256, 1), 256, 0, stream>>>(x, 4, hbar, 8, w_self0, w_edge0, nullptr,
                                                feat0, 16384, 64, 1);
  // --- FPS level 1 + downsample ---
  fps_kernel<8192, 4096><<<2, 1024, 0, stream>>>(pos, idx1, pos1);
  gather_kernel<<<2048, 256, 0, stream>>>(feat0, idx1, 4096, 8192, 64, 2, feat0g);
  knn_kernel<4><<<dim3(64, 2), 256, 0, stream>>>(pos1, 4096, knn1);
  hbar_kernel<<<2176, 256, 0, stream>>>(feat0g, pos1, knn1, 4096, 64, 2, hbar);
  gemm_kernel<<<dim3(128, 2), 256, 0, stream>>>(feat0g, 64, hbar, 68, w_self1, w_edge1, nullptr,
                                                feat1, 8192, 128, 1);
  // --- FPS level 2 + downsample ---
  fps_kernel<4096, 2048><<<2, 1024, 0, stream>>>(pos1, idx2, pos2);
  gather_kernel<<<2048, 256, 0, stream>>>(feat1, idx2, 2048, 4096, 128, 2, feat1g);
  knn_kernel<4><<<dim3(32, 2), 256, 0, stream>>>(pos2, 2048, knn2);
  hbar_kernel<<<2112, 256, 0, stream>>>(feat1g, pos2, knn2, 2048, 128, 2, hbar);
  gemm_kernel<<<dim3(64, 4), 256, 0, stream>>>(feat1g, 128, hbar, 132, w_self2, w_edge2, nullptr,
                                               feat2, 4096, 256, 1);
  // --- up level 1: interp(feat2)->pos1, concat feat1, linear, edge conv ---
  three_nn_kernel<<<dim3(16, 2), 256, 0, stream>>>(pos1, pos2, 4096, 2048, nn1i, nn1w);
  interp_kernel<<<8192, 256, 0, stream>>>(feat2, nn1i, nn1w, 4096, 2048, 256, 2, interp);
  gemm_kernel<<<dim3(128, 2), 256, 0, stream>>>(interp, 256, feat1, 128,
                                                w_up1, w_up1 + (size_t)256 * 128, b_up1,
                                                fupa, 8192, 128, 1);
  hbar_kernel<<<4224, 256, 0, stream>>>(fupa, pos1, knn1, 4096, 128, 2, hbar);
  gemm_kernel<<<dim3(128, 2), 256, 0, stream>>>(fupa, 128, hbar, 132, w_upc1s, w_upc1e, nullptr,
                                                fup1, 8192, 128, 1);
  // --- up level 0: interp(fup1)->pos0, concat feat0, linear, edge conv ---
  three_nn_kernel<<<dim3(32, 2), 256, 0, stream>>>(pos, pos1, 8192, 4096, nn0i, nn0w);
  interp_kernel<<<8192, 256, 0, stream>>>(fup1, nn0i, nn0w, 8192, 4096, 128, 2, interp);
  gemm_kernel<<<dim3(256, 1), 256, 0, stream>>>(interp, 128, feat0, 64,
                                                w_up0, w_up0 + (size_t)128 * 64, b_up0,
                                                fupa, 16384, 64, 1);
  hbar_kernel<<<4352, 256, 0, stream>>>(fupa, pos, knn0, 8192, 64, 2, hbar);
  gemm_kernel<<<dim3(256, 1), 256, 0, stream>>>(fupa, 64, hbar, 68, w_upc0s, w_upc0e, nullptr,
                                                fout, 16384, 64, 1);
  // --- final projection ---
  gemm_kernel<<<dim3(256, 2), 256, 0, stream>>>(fout, 64, nullptr, 0, w_out, nullptr, b_out,
                                                out, 16384, 128, 0);
}

// Round 2
// 10318.784 us; speedup vs baseline: 1.0430x; 1.0430x over previous
//
#include <hip/hip_runtime.h>
#include <cstdint>

static __device__ __forceinline__ float leakyf(float v) { return v >= 0.f ? v : 0.2f * v; }

// ------------------------------------------------------------------
// Pack [M,3] positions into float4(x,y,z,|p|^2). ss association (x*x+y*y)+z*z
// must match the query-side qq usage in knn/three_nn.
__global__ void pack_kernel(const float* __restrict__ pos, int total, float4* __restrict__ out)
{
  int i = blockIdx.x * 256 + threadIdx.x;
  if (i >= total) return;
  float x = pos[i*3+0], y = pos[i*3+1], z = pos[i*3+2];
  out[i] = make_float4(x, y, z, (x*x + y*y) + z*z);
}

// ------------------------------------------------------------------
// Furthest point sampling (exact, matches jax scan semantics):
// out[0]=0; for it in 1..NP-1: dists=min(dists, d(.,pos[out[it-1]])); out[it]=argmax (first max).
// One block (1024 threads) per batch. Single barrier/iter: double-buffered partials,
// every wave redundantly reduces the 16 wave-partials (bit-identical).
template<int N, int NPOINT>
__global__ __launch_bounds__(1024) void fps_kernel(const float* __restrict__ pos,
                                                   int* __restrict__ out_idx,
                                                   float* __restrict__ out_pos,
                                                   float4* __restrict__ out_pp)
{
  constexpr int NPT = N / 1024;
  const int b = blockIdx.x;
  const float* P = pos + (size_t)b * N * 3;
  int* oi = out_idx + (size_t)b * NPOINT;
  float* op = out_pos + (size_t)b * NPOINT * 3;
  float4* opp = out_pp + (size_t)b * NPOINT;

  __shared__ float sx[N];
  __shared__ float sy[N];
  __shared__ float sz[N];
  __shared__ float red_d[2][16];
  __shared__ int   red_i[2][16];

  const int t = threadIdx.x;
  const int lane = t & 63;
  const int wv = t >> 6;
  float px[NPT], py[NPT], pz[NPT], dist[NPT];
#pragma unroll
  for (int j = 0; j < NPT; ++j) {
    int i = t + j * 1024;
    float x = P[i*3+0], y = P[i*3+1], z = P[i*3+2];
    sx[i] = x; sy[i] = y; sz[i] = z;
    px[j] = x; py[j] = y; pz[j] = z;
    dist[j] = 1e10f;
  }
  if (t == 0) oi[0] = 0;
  __syncthreads();

  int far = 0;
  for (int it = 1; it < NPOINT; ++it) {
    const float cx = sx[far], cy = sy[far], cz = sz[far];
    float bd = -1.f; int bi = 0x7fffffff;
#pragma unroll
    for (int j = 0; j < NPT; ++j) {
      float dx = px[j] - cx, dy = py[j] - cy, dz = pz[j] - cz;
      float d = fmaf(dz, dz, fmaf(dy, dy, dx * dx));
      float nd = fminf(dist[j], d);
      dist[j] = nd;
      bool better = nd > bd;
      bd = better ? nd : bd;
      bi = better ? (t + j * 1024) : bi;
    }
    // wave (64-lane) argmax, ties -> lower index
#pragma unroll
    for (int s = 1; s < 64; s <<= 1) {
      float od = __shfl_xor(bd, s);
      int   ob = __shfl_xor(bi, s);
      if (od > bd || (od == bd && ob < bi)) { bd = od; bi = ob; }
    }
    const int par = it & 1;
    if (lane == 0) { red_d[par][wv] = bd; red_i[par][wv] = bi; }
    __syncthreads();
    // all waves redundantly reduce the 16 partials (no second barrier needed;
    // double-buffer protects against next iteration's overwrite)
    float rd = (lane < 16) ? red_d[par][lane] : -1.f;
    int   ri = (lane < 16) ? red_i[par][lane] : 0x7fffffff;
#pragma unroll
    for (int s = 1; s < 16; s <<= 1) {
      float od = __shfl_xor(rd, s);
      int   ob = __shfl_xor(ri, s);
      if (od > rd || (od == rd && ob < ri)) { rd = od; ri = ob; }
    }
    far = __shfl(ri, 0);
    if (t == 0) oi[it] = far;
  }
  __syncthreads();
  // gather sampled positions (plain + packed)
  for (int i = t; i < NPOINT; i += 1024) {
    int id = oi[i];
    float x = sx[id], y = sy[id], z = sz[id];
    op[i*3+0] = x; op[i*3+1] = y; op[i*3+2] = z;
    opp[i] = make_float4(x, y, z, (x*x + y*y) + z*z);
  }
}

// ------------------------------------------------------------------
// Self-KNN (K=16), stable (d, idx) selection identical to lax.top_k(-d).
// G=16 segments per query; per-seg sorted top-16 in registers; segments merged
// in-wave via shfl_xor bitonic rounds with lexicographic (d, idx) comparator.
template<int G>
__global__ __launch_bounds__(256) void knn_kernel(const float4* __restrict__ pp, int M,
                                                  int* __restrict__ out)
{
  const int b = blockIdx.y;
  const float4* P = pp + (size_t)b * M;
  const int tid = threadIdx.x;
  constexpr int QPB = 256 / G;
  const int q = blockIdx.x * QPB + tid / G;
  const int seg = tid % G;

  __shared__ float4 tile[512];

  const float4 qp = P[q];
  const float qx = qp.x, qy = qp.y, qz = qp.z, qq = qp.w;

  float a[16]; int id[16];
#pragma unroll
  for (int j = 0; j < 16; ++j) { a[j] = 3.4e38f; id[j] = 0x7fffffff; }

  for (int t0 = 0; t0 < M; t0 += 512) {
    __syncthreads();
    tile[tid]       = P[t0 + tid];
    tile[tid + 256] = P[t0 + tid + 256];
    __syncthreads();
#pragma unroll 4
    for (int i = seg; i < 512; i += G) {
      float4 c = tile[i];
      float d = (qq + c.w) - 2.f * ((qx*c.x + qy*c.y) + qz*c.z);
      int gi = t0 + i;
      if (d < a[15]) {               // insertion, stable: ties keep earlier idx
        bool cc[16];
#pragma unroll
        for (int j = 0; j < 16; ++j) cc[j] = d < a[j];
#pragma unroll
        for (int j = 15; j >= 1; --j) {
          a[j]  = cc[j-1] ? a[j-1]  : (cc[j] ? d  : a[j]);
          id[j] = cc[j-1] ? id[j-1] : (cc[j] ? gi : id[j]);
        }
        if (cc[0]) { a[0] = d; id[0] = gi; }
      }
    }
  }
  // butterfly merge across G segments: exchange, take bitonic lower half,
  // re-sort with a bitonic merge network. All static register indices.
#pragma unroll
  for (int s = G/2; s >= 1; s >>= 1) {
    float bd[16]; int bi[16];
#pragma unroll
    for (int j = 0; j < 16; ++j) { bd[j] = __shfl_xor(a[j], s); bi[j] = __shfl_xor(id[j], s); }
#pragma unroll
    for (int j = 0; j < 16; ++j) {       // lower half of bitonic 32-seq [a asc | b desc]
      float od = bd[15-j]; int ob = bi[15-j];
      bool take = (od < a[j]) || (od == a[j] && ob < id[j]);
      a[j]  = take ? od : a[j];
      id[j] = take ? ob : id[j];
    }
#pragma unroll
    for (int st = 8; st >= 1; st >>= 1) { // bitonic merge: sort the bitonic 16-seq
#pragma unroll
      for (int j = 0; j < 16; ++j) {
        if ((j & st) == 0) {
          const int j2 = j + st;
          bool sw = (a[j2] < a[j]) || (a[j2] == a[j] && id[j2] < id[j]);
          float lod = sw ? a[j2] : a[j];  int loi = sw ? id[j2] : id[j];
          float hid = sw ? a[j]  : a[j2]; int hii = sw ? id[j]  : id[j2];
          a[j] = lod; id[j] = loi; a[j2] = hid; id[j2] = hii;
        }
      }
    }
  }
  if (seg == 0) {
    int* opp = out + ((size_t)b * M + q) * 16;
#pragma unroll
    for (int j = 0; j < 16; ++j) opp[j] = id[j];
  }
}

// ------------------------------------------------------------------
// three_nn + interpolation weights. Same G-segmented structure with register
// top-4 lists (4th slot only to make the bitonic trick power-of-two).
template<int G>
__global__ __launch_bounds__(256) void three_nn_kernel(const float4* __restrict__ qpp,
                                                       const float4* __restrict__ kpp,
                                                       int Mq, int Mk,
                                                       int* __restrict__ oidx, float* __restrict__ ow)
{
  const int b = blockIdx.y;
  const float4* Q  = qpp + (size_t)b * Mq;
  const float4* Kp = kpp + (size_t)b * Mk;
  const int tid = threadIdx.x;
  constexpr int QPB = 256 / G;
  const int q = blockIdx.x * QPB + tid / G;
  const int seg = tid % G;

  __shared__ float4 tile[512];

  const float4 qp = Q[q];
  const float qx = qp.x, qy = qp.y, qz = qp.z, qq = qp.w;

  float a[4]; int id[4];
#pragma unroll
  for (int j = 0; j < 4; ++j) { a[j] = 3.4e38f; id[j] = 0x7fffffff; }

  for (int t0 = 0; t0 < Mk; t0 += 512) {
    __syncthreads();
    tile[tid]       = Kp[t0 + tid];
    tile[tid + 256] = Kp[t0 + tid + 256];
    __syncthreads();
#pragma unroll 4
    for (int i = seg; i < 512; i += G) {
      float4 c = tile[i];
      float d = (qq + c.w) - 2.f * ((qx*c.x + qy*c.y) + qz*c.z);
      int gi = t0 + i;
      if (d < a[3]) {
        bool c0 = d < a[0], c1 = d < a[1], c2 = d < a[2];
        a[3]  = c2 ? a[2]  : d;              id[3] = c2 ? id[2] : gi;
        a[2]  = c1 ? a[1]  : (c2 ? d  : a[2]); id[2] = c1 ? id[1] : (c2 ? gi : id[2]);
        a[1]  = c0 ? a[0]  : (c1 ? d  : a[1]); id[1] = c0 ? id[0] : (c1 ? gi : id[1]);
        if (c0) { a[0] = d; id[0] = gi; }
      }
    }
  }
#pragma unroll
  for (int s = G/2; s >= 1; s >>= 1) {
    float bd[4]; int bi[4];
#pragma unroll
    for (int j = 0; j < 4; ++j) { bd[j] = __shfl_xor(a[j], s); bi[j] = __shfl_xor(id[j], s); }
#pragma unroll
    for (int j = 0; j < 4; ++j) {
      float od = bd[3-j]; int ob = bi[3-j];
      bool take = (od < a[j]) || (od == a[j] && ob < id[j]);
      a[j]  = take ? od : a[j];
      id[j] = take ? ob : id[j];
    }
#pragma unroll
    for (int st = 2; st >= 1; st >>= 1) {
#pragma unroll
      for (int j = 0; j < 4; ++j) {
        if ((j & st) == 0) {
          const int j2 = j + st;
          bool sw = (a[j2] < a[j]) || (a[j2] == a[j] && id[j2] < id[j]);
          float lod = sw ? a[j2] : a[j];  int loi = sw ? id[j2] : id[j];
          float hid = sw ? a[j]  : a[j2]; int hii = sw ? id[j]  : id[j2];
          a[j] = lod; id[j] = loi; a[j2] = hid; id[j2] = hii;
        }
      }
    }
  }
  if (seg == 0) {
    float d0 = fmaxf(a[0], 0.f), d1 = fmaxf(a[1], 0.f), d2 = fmaxf(a[2], 0.f);
    float r0 = 1.f/(d0 + 1e-8f), r1 = 1.f/(d1 + 1e-8f), r2 = 1.f/(d2 + 1e-8f);
    float s = (r0 + r1) + r2;
    size_t o = ((size_t)b * Mq + q) * 3;
    oidx[o+0] = id[0]; oidx[o+1] = id[1]; oidx[o+2] = id[2];
    ow[o+0] = r0/s; ow[o+1] = r1/s; ow[o+2] = r2/s;
  }
}

// ------------------------------------------------------------------
// Edge-conv neighbor mean: hbar[p] = [mean_k x[n_k], mean_k (pos_p - pos_nk), mean_k |rel|^2]
__global__ void hbar_kernel(const float* __restrict__ x, const float* __restrict__ pos,
                            const int* __restrict__ idx, int Mlvl, int C, int B,
                            float* __restrict__ out)
{
  const int Ct = C + 4;
  const int tot = B * Mlvl * Ct;
  int e = blockIdx.x * 256 + threadIdx.x;
  if (e >= tot) return;
  const int c  = e % Ct;
  const int p  = e / Ct;
  const int b  = p / Mlvl;
  const int lm = p % Mlvl;
  const int* ip = idx + (size_t)p * 16;
  float s = 0.f;
  if (c < C) {
    const float* xb = x + (size_t)b * Mlvl * C;
#pragma unroll 4
    for (int k = 0; k < 16; ++k) s += xb[(size_t)ip[k] * C + c];
  } else if (c < C + 3) {
    const int dd = c - C;
    const float* pb = pos + (size_t)b * Mlvl * 3;
    const float pc = pb[lm*3 + dd];
#pragma unroll 4
    for (int k = 0; k < 16; ++k) s += pc - pb[ip[k]*3 + dd];
  } else {
    const float* pb = pos + (size_t)b * Mlvl * 3;
    const float px = pb[lm*3+0], py = pb[lm*3+1], pz = pb[lm*3+2];
#pragma unroll 4
    for (int k = 0; k < 16; ++k) {
      int n = ip[k];
      float dx = px - pb[n*3+0], dy = py - pb[n*3+1], dz = pz - pb[n*3+2];
      s += (dx*dx + dy*dy) + dz*dz;
    }
  }
  out[e] = s * 0.0625f;
}

// ------------------------------------------------------------------
__global__ void interp_kernel(const float* __restrict__ f, const int* __restrict__ nidx,
                              const float* __restrict__ nw, int Mq, int Msub, int C, int B,
                              float* __restrict__ out)
{
  const int tot = B * Mq * C;
  int e = blockIdx.x * 256 + threadIdx.x;
  if (e >= tot) return;
  const int c = e % C;
  const int p = e / C;
  const int b = p / Mq;
  const float* fb = f + (size_t)b * Msub * C;
  const int* ip   = nidx + (size_t)p * 3;
  const float* wp = nw   + (size_t)p * 3;
  out[e] = (wp[0] * fb[(size_t)ip[0]*C + c] + wp[1] * fb[(size_t)ip[1]*C + c])
         +  wp[2] * fb[(size_t)ip[2]*C + c];
}

// ------------------------------------------------------------------
__global__ void gather_kernel(const float* __restrict__ src, const int* __restrict__ idx,
                              int Mq, int Msrc, int C, int B, float* __restrict__ dst)
{
  const int tot = B * Mq * C;
  int e = blockIdx.x * 256 + threadIdx.x;
  if (e >= tot) return;
  const int c = e % C;
  const int p = e / C;
  const int b = p / Mq;
  dst[e] = src[((size_t)b * Msrc + idx[p]) * C + c];
}

// ------------------------------------------------------------------
// Fused GEMM: out[M,F] = act( A[M,Ka]@W1[Ka,F] + B2[M,Kb]@W2[Kb,F] + bias )
// 64x64 tile, BK=16, 256 threads, 4x4 micro-tile. M,F multiples of 64; K zero-padded.
__global__ __launch_bounds__(256) void gemm_kernel(const float* __restrict__ A, int Ka,
                                                   const float* __restrict__ B2, int Kb,
                                                   const float* __restrict__ W1,
                                                   const float* __restrict__ W2,
                                                   const float* __restrict__ bias,
                                                   float* __restrict__ out,
                                                   int M, int F, int act)
{
  __shared__ __align__(16) float As[16][64];
  __shared__ __align__(16) float Ws[16][64];
  const int tid  = threadIdx.x;
  const int row0 = blockIdx.x * 64;
  const int col0 = blockIdx.y * 64;
  const int tx = tid & 15, ty = tid >> 4;
  const int K = Ka + Kb;
  float acc[4][4] = {};
  for (int k0 = 0; k0 < K; k0 += 16) {
#pragma unroll
    for (int i = 0; i < 4; ++i) {
      int e = tid + i * 256;
      int m = e & 63, kk = e >> 6;
      int k = k0 + kk;
      float v = 0.f;
      if (k < Ka)     v = A [(size_t)(row0 + m) * Ka + k];
      else if (k < K) v = B2[(size_t)(row0 + m) * Kb + (k - Ka)];
      As[kk][m] = v;
      float wv = 0.f;
      if (k < Ka)     wv = W1[(size_t)k * F + col0 + m];
      else if (k < K) wv = W2[(size_t)(k - Ka) * F + col0 + m];
      Ws[kk][m] = wv;
    }
    __syncthreads();
#pragma unroll
    for (int kk = 0; kk < 16; ++kk) {
      const float4 a4 = *reinterpret_cast<const float4*>(&As[kk][ty * 4]);
      const float4 b4 = *reinterpret_cast<const float4*>(&Ws[kk][tx * 4]);
      const float av[4] = {a4.x, a4.y, a4.z, a4.w};
      const float bv[4] = {b4.x, b4.y, b4.z, b4.w};
#pragma unroll
      for (int i2 = 0; i2 < 4; ++i2)
#pragma unroll
        for (int j2 = 0; j2 < 4; ++j2)
          acc[i2][j2] = fmaf(av[i2], bv[j2], acc[i2][j2]);
    }
    __syncthreads();
  }
#pragma unroll
  for (int i2 = 0; i2 < 4; ++i2) {
    int r = row0 + ty * 4 + i2;
#pragma unroll
    for (int j2 = 0; j2 < 4; ++j2) {
      int cc = col0 + tx * 4 + j2;
      float v = acc[i2][j2];
      if (bias) v += bias[cc];
      if (act)  v = leakyf(v);
      out[(size_t)r * F + cc] = v;
    }
  }
}

// ------------------------------------------------------------------
extern "C" void kernel_launch(void* const* d_in, const int* in_sizes, int n_in,
                              void* d_out, int out_size, void* d_ws, size_t ws_size,
                              hipStream_t stream)
{
  (void)in_sizes; (void)n_in; (void)out_size; (void)ws_size;
  const float* x          = (const float*)d_in[0];   // [2,8192,4]
  const float* pos        = (const float*)d_in[1];   // [2,8192,3]
  const float* w_self0    = (const float*)d_in[2];   // [4,64]
  const float* w_edge0    = (const float*)d_in[3];   // [8,64]
  const float* w_self1    = (const float*)d_in[4];   // [64,128]
  const float* w_edge1    = (const float*)d_in[5];   // [68,128]
  const float* w_self2    = (const float*)d_in[6];   // [128,256]
  const float* w_edge2    = (const float*)d_in[7];   // [132,256]
  const float* w_up1      = (const float*)d_in[8];   // [384,128]
  const float* b_up1      = (const float*)d_in[9];   // [128]
  const float* w_upc1s    = (const float*)d_in[10];  // [128,128]
  const float* w_upc1e    = (const float*)d_in[11];  // [132,128]
  const float* w_up0      = (const float*)d_in[12];  // [192,64]
  const float* b_up0      = (const float*)d_in[13];  // [64]
  const float* w_upc0s    = (const float*)d_in[14];  // [64,64]
  const float* w_upc0e    = (const float*)d_in[15];  // [68,64]
  const float* w_out      = (const float*)d_in[16];  // [64,128]
  const float* b_out      = (const float*)d_in[17];  // [128]
  float* out = (float*)d_out;                        // [2,8192,128]

  char* ws = (char*)d_ws;
  size_t off = 0;
  auto alloc = [&](size_t nbytes) -> void* {
    off = (off + 255) & ~(size_t)255;
    void* p = ws + off;
    off += nbytes;
    return p;
  };
  int*    knn0   = (int*)   alloc((size_t)2*8192*16*4);
  int*    knn1   = (int*)   alloc((size_t)2*4096*16*4);
  int*    knn2   = (int*)   alloc((size_t)2*2048*16*4);
  int*    idx1   = (int*)   alloc((size_t)2*4096*4);
  int*    idx2   = (int*)   alloc((size_t)2*2048*4);
  float*  pos1   = (float*) alloc((size_t)2*4096*3*4);
  float*  pos2   = (float*) alloc((size_t)2*2048*3*4);
  float4* pp0    = (float4*)alloc((size_t)2*8192*16);
  float4* pp1    = (float4*)alloc((size_t)2*4096*16);
  float4* pp2    = (float4*)alloc((size_t)2*2048*16);
  float*  feat0  = (float*) alloc((size_t)2*8192*64*4);
  float*  feat0g = (float*) alloc((size_t)2*4096*64*4);
  float*  feat1  = (float*) alloc((size_t)2*4096*128*4);
  float*  feat1g = (float*) alloc((size_t)2*2048*128*4);
  float*  feat2  = (float*) alloc((size_t)2*2048*256*4);
  int*    nn1i   = (int*)   alloc((size_t)2*4096*3*4);
  float*  nn1w   = (float*) alloc((size_t)2*4096*3*4);
  int*    nn0i   = (int*)   alloc((size_t)2*8192*3*4);
  float*  nn0w   = (float*) alloc((size_t)2*8192*3*4);
  float*  interp = (float*) alloc((size_t)2*4096*256*4);  // reused for interp0 (same size)
  float*  hbar   = (float*) alloc((size_t)2*8192*68*4);   // max of all hbar stages
  float*  fupa   = (float*) alloc((size_t)2*4096*128*4);  // fup1a, later fup0a (same size)
  float*  fup1   = (float*) alloc((size_t)2*4096*128*4);
  float*  fout   = (float*) alloc((size_t)2*8192*64*4);

  // --- packed pos level 0 ---
  pack_kernel<<<64, 256, 0, stream>>>(pos, 2*8192, pp0);
  // --- level 0: knn + edge conv ---
  knn_kernel<16><<<dim3(512, 2), 256, 0, stream>>>(pp0, 8192, knn0);
  hbar_kernel<<<512, 256, 0, stream>>>(x, pos, knn0, 8192, 4, 2, hbar);
  gemm_kernel<<<dim3(256, 1), 256, 0, stream>>>(x, 4, hbar, 8, w_self0, w_edge0, nullptr,
                                                feat0, 16384, 64, 1);
  // --- FPS level 1 + downsample ---
  fps_kernel<8192, 4096><<<2, 1024, 0, stream>>>(pos, idx1, pos1, pp1);
  gather_kernel<<<2048, 256, 0, stream>>>(feat0, idx1, 4096, 8192, 64, 2, feat0g);
  knn_kernel<16><<<dim3(256, 2), 256, 0, stream>>>(pp1, 4096, knn1);
  hbar_kernel<<<2176, 256, 0, stream>>>(feat0g, pos1, knn1, 4096, 64, 2, hbar);
  gemm_kernel<<<dim3(128, 2), 256, 0, stream>>>(feat0g, 64, hbar, 68, w_self1, w_edge1, nullptr,
                                                feat1, 8192, 128, 1);
  // --- FPS level 2 + downsample ---
  fps_kernel<4096, 2048><<<2, 1024, 0, stream>>>(pos1, idx2, pos2, pp2);
  gather_kernel<<<2048, 256, 0, stream>>>(feat1, idx2, 2048, 4096, 128, 2, feat1g);
  knn_kernel<16><<<dim3(128, 2), 256, 0, stream>>>(pp2, 2048, knn2);
  hbar_kernel<<<2112, 256, 0, stream>>>(feat1g, pos2, knn2, 2048, 128, 2, hbar);
  gemm_kernel<<<dim3(64, 4), 256, 0, stream>>>(feat1g, 128, hbar, 132, w_self2, w_edge2, nullptr,
                                               feat2, 4096, 256, 1);
  // --- up level 1: interp(feat2)->pos1, concat feat1, linear, edge conv ---
  three_nn_kernel<16><<<dim3(256, 2), 256, 0, stream>>>(pp1, pp2, 4096, 2048, nn1i, nn1w);
  interp_kernel<<<8192, 256, 0, stream>>>(feat2, nn1i, nn1w, 4096, 2048, 256, 2, interp);
  gemm_kernel<<<dim3(128, 2), 256, 0, stream>>>(interp, 256, feat1, 128,
                                                w_up1, w_up1 + (size_t)256 * 128, b_up1,
                                                fupa, 8192, 128, 1);
  hbar_kernel<<<4224, 256, 0, stream>>>(fupa, pos1, knn1, 4096, 128, 2, hbar);
  gemm_kernel<<<dim3(128, 2), 256, 0, stream>>>(fupa, 128, hbar, 132, w_upc1s, w_upc1e, nullptr,
                                                fup1, 8192, 128, 1);
  // --- up level 0: interp(fup1)->pos0, concat feat0, linear, edge conv ---
  three_nn_kernel<16><<<dim3(512, 2), 256, 0, stream>>>(pp0, pp1, 8192, 4096, nn0i, nn0w);
  interp_kernel<<<8192, 256, 0, stream>>>(fup1, nn0i, nn0w, 8192, 4096, 128, 2, interp);
  gemm_kernel<<<dim3(256, 1), 256, 0, stream>>>(interp, 128, feat0, 64,
                                                w_up0, w_up0 + (size_t)128 * 64, b_up0,
                                                fupa, 16384, 64, 1);
  hbar_kernel<<<4352, 256, 0, stream>>>(fupa, pos, knn0, 8192, 64, 2, hbar);
  gemm_kernel<<<dim3(256, 1), 256, 0, stream>>>(fupa, 64, hbar, 68, w_upc0s, w_upc0e, nullptr,
                                                fout, 16384, 64, 1);
  // --- final projection ---
  gemm_kernel<<<dim3(256, 2), 256, 0, stream>>>(fout, 64, nullptr, 0, w_out, nullptr, b_out,
                                                out, 16384, 128, 0);
}

// Round 3
// 7391.110 us; speedup vs baseline: 1.4561x; 1.3961x over previous
//
#include <hip/hip_runtime.h>
#include <cstdint>

static __device__ __forceinline__ float leakyf(float v) { return v >= 0.f ? v : 0.2f * v; }

// ------------------------------------------------------------------
// Pack [M,3] positions into float4(x,y,z,|p|^2). ss association (x*x+y*y)+z*z
// must match the query-side qq usage in knn/three_nn.
__global__ void pack_kernel(const float* __restrict__ pos, int total, float4* __restrict__ out)
{
  int i = blockIdx.x * 256 + threadIdx.x;
  if (i >= total) return;
  float x = pos[i*3+0], y = pos[i*3+1], z = pos[i*3+2];
  out[i] = make_float4(x, y, z, (x*x + y*y) + z*z);
}

// ------------------------------------------------------------------
// Furthest point sampling (exact, matches jax scan semantics):
// out[0]=0; for it in 1..NP-1: dists=min(dists, d(.,pos[out[it-1]])); out[it]=argmax (first max).
// One block (512 threads = 8 waves) per batch.
// Key design: (d,idx) packed into u64 => max is exact lexicographic (d desc, idx asc),
// associative, so register-tree + wave-butterfly + 8-partial VALU max is bit-exact.
// Single barrier per iteration (double-buffered partials).
// Sampled outputs are written in-loop: at iter `it` every thread holds sample it-1's
// coords (the current center), so thread (it-1)%512 emits it. No epilogue.
template<int N, int NPOINT>
__global__ __launch_bounds__(512) void fps_kernel(const float* __restrict__ pos,
                                                  int* __restrict__ out_idx,
                                                  float* __restrict__ out_pos,
                                                  float4* __restrict__ out_pp)
{
  constexpr int BLOCK = 512;
  constexpr int NPT = N / BLOCK;
  const int b = blockIdx.x;
  const float* P = pos + (size_t)b * N * 3;
  int* oi = out_idx + (size_t)b * NPOINT;
  float* op = out_pos + (size_t)b * NPOINT * 3;
  float4* opp = out_pp + (size_t)b * NPOINT;

  __shared__ float4 spos[N];
  __shared__ unsigned long long redk[2][8];

  const int t = threadIdx.x;
  const int lane = t & 63;
  const int wv = t >> 6;

  float px[NPT], py[NPT], pz[NPT], dist[NPT];
  unsigned iv[NPT];  // precomputed 0xFFFFFFFF - global_idx (tie-break payload)
#pragma unroll
  for (int j = 0; j < NPT; ++j) {
    int i = t + j * BLOCK;
    float x = P[i*3+0], y = P[i*3+1], z = P[i*3+2];
    spos[i] = make_float4(x, y, z, (x*x + y*y) + z*z);
    px[j] = x; py[j] = y; pz[j] = z; dist[j] = 1e10f;
    iv[j] = 0xFFFFFFFFu - (unsigned)i;
  }
  if (t == 0) oi[0] = 0;
  __syncthreads();

  int far = 0;
  for (int it = 1; it < NPOINT; ++it) {
    const float4 c = spos[far];              // one b128 broadcast read
    if (t == ((it - 1) & (BLOCK - 1))) {     // emit sample it-1 (coords = current center)
      op[(it-1)*3+0] = c.x; op[(it-1)*3+1] = c.y; op[(it-1)*3+2] = c.z;
      opp[it-1] = c;
    }
    unsigned long long k[NPT];
#pragma unroll
    for (int j = 0; j < NPT; ++j) {
      float dx = px[j] - c.x, dy = py[j] - c.y, dz = pz[j] - c.z;
      float d  = fmaf(dz, dz, fmaf(dy, dy, dx * dx));
      float nd = fminf(dist[j], d);
      dist[j] = nd;
      k[j] = ((unsigned long long)__float_as_uint(nd) << 32) | (unsigned long long)iv[j];
    }
    // register tree max (static indices)
#pragma unroll
    for (int s = NPT / 2; s >= 1; s >>= 1)
#pragma unroll
      for (int j = 0; j < s; ++j)
        if (k[j + s] > k[j]) k[j] = k[j + s];
    unsigned long long key = k[0];
    // wave butterfly max
#pragma unroll
    for (int s = 1; s < 64; s <<= 1) {
      unsigned long long ok = __shfl_xor(key, s);
      if (ok > key) key = ok;
    }
    const int par = it & 1;
    if (lane == 0) redk[par][wv] = key;
    __syncthreads();
    // all threads max the 8 wave partials in VALU (no second shfl chain)
#pragma unroll
    for (int w2 = 0; w2 < 8; ++w2) {
      unsigned long long ok = redk[par][w2];
      if (ok > key) key = ok;
    }
    far = (int)(0xFFFFFFFFu - (unsigned)(key & 0xFFFFFFFFull));
    if (t == 0) oi[it] = far;
  }
  // flush the last sample
  {
    const float4 c = spos[far];
    if (t == ((NPOINT - 1) & (BLOCK - 1))) {
      op[(NPOINT-1)*3+0] = c.x; op[(NPOINT-1)*3+1] = c.y; op[(NPOINT-1)*3+2] = c.z;
      opp[NPOINT-1] = c;
    }
  }
}

// ------------------------------------------------------------------
// Self-KNN (K=16), stable (d, idx) selection identical to lax.top_k(-d).
// G=16 segments per query; per-seg sorted top-16 in registers; segments merged
// in-wave via shfl_xor bitonic rounds with lexicographic (d, idx) comparator.
template<int G>
__global__ __launch_bounds__(256) void knn_kernel(const float4* __restrict__ pp, int M,
                                                  int* __restrict__ out)
{
  const int b = blockIdx.y;
  const float4* P = pp + (size_t)b * M;
  const int tid = threadIdx.x;
  constexpr int QPB = 256 / G;
  const int q = blockIdx.x * QPB + tid / G;
  const int seg = tid % G;

  __shared__ float4 tile[512];

  const float4 qp = P[q];
  const float qx = qp.x, qy = qp.y, qz = qp.z, qq = qp.w;

  float a[16]; int id[16];
#pragma unroll
  for (int j = 0; j < 16; ++j) { a[j] = 3.4e38f; id[j] = 0x7fffffff; }

  for (int t0 = 0; t0 < M; t0 += 512) {
    __syncthreads();
    tile[tid]       = P[t0 + tid];
    tile[tid + 256] = P[t0 + tid + 256];
    __syncthreads();
#pragma unroll 4
    for (int i = seg; i < 512; i += G) {
      float4 c = tile[i];
      float d = (qq + c.w) - 2.f * ((qx*c.x + qy*c.y) + qz*c.z);
      int gi = t0 + i;
      if (d < a[15]) {               // insertion, stable: ties keep earlier idx
        bool cc[16];
#pragma unroll
        for (int j = 0; j < 16; ++j) cc[j] = d < a[j];
#pragma unroll
        for (int j = 15; j >= 1; --j) {
          a[j]  = cc[j-1] ? a[j-1]  : (cc[j] ? d  : a[j]);
          id[j] = cc[j-1] ? id[j-1] : (cc[j] ? gi : id[j]);
        }
        if (cc[0]) { a[0] = d; id[0] = gi; }
      }
    }
  }
  // butterfly merge across G segments: exchange, take bitonic lower half,
  // re-sort with a bitonic merge network. All static register indices.
#pragma unroll
  for (int s = G/2; s >= 1; s >>= 1) {
    float bd[16]; int bi[16];
#pragma unroll
    for (int j = 0; j < 16; ++j) { bd[j] = __shfl_xor(a[j], s); bi[j] = __shfl_xor(id[j], s); }
#pragma unroll
    for (int j = 0; j < 16; ++j) {       // lower half of bitonic 32-seq [a asc | b desc]
      float od = bd[15-j]; int ob = bi[15-j];
      bool take = (od < a[j]) || (od == a[j] && ob < id[j]);
      a[j]  = take ? od : a[j];
      id[j] = take ? ob : id[j];
    }
#pragma unroll
    for (int st = 8; st >= 1; st >>= 1) { // bitonic merge: sort the bitonic 16-seq
#pragma unroll
      for (int j = 0; j < 16; ++j) {
        if ((j & st) == 0) {
          const int j2 = j + st;
          bool sw = (a[j2] < a[j]) || (a[j2] == a[j] && id[j2] < id[j]);
          float lod = sw ? a[j2] : a[j];  int loi = sw ? id[j2] : id[j];
          float hid = sw ? a[j]  : a[j2]; int hii = sw ? id[j]  : id[j2];
          a[j] = lod; id[j] = loi; a[j2] = hid; id[j2] = hii;
        }
      }
    }
  }
  if (seg == 0) {
    int* opp = out + ((size_t)b * M + q) * 16;
#pragma unroll
    for (int j = 0; j < 16; ++j) opp[j] = id[j];
  }
}

// ------------------------------------------------------------------
// three_nn + interpolation weights. Same G-segmented structure with register
// top-4 lists (4th slot only to make the bitonic trick power-of-two).
template<int G>
__global__ __launch_bounds__(256) void three_nn_kernel(const float4* __restrict__ qpp,
                                                       const float4* __restrict__ kpp,
                                                       int Mq, int Mk,
                                                       int* __restrict__ oidx, float* __restrict__ ow)
{
  const int b = blockIdx.y;
  const float4* Q  = qpp + (size_t)b * Mq;
  const float4* Kp = kpp + (size_t)b * Mk;
  const int tid = threadIdx.x;
  constexpr int QPB = 256 / G;
  const int q = blockIdx.x * QPB + tid / G;
  const int seg = tid % G;

  __shared__ float4 tile[512];

  const float4 qp = Q[q];
  const float qx = qp.x, qy = qp.y, qz = qp.z, qq = qp.w;

  float a[4]; int id[4];
#pragma unroll
  for (int j = 0; j < 4; ++j) { a[j] = 3.4e38f; id[j] = 0x7fffffff; }

  for (int t0 = 0; t0 < Mk; t0 += 512) {
    __syncthreads();
    tile[tid]       = Kp[t0 + tid];
    tile[tid + 256] = Kp[t0 + tid + 256];
    __syncthreads();
#pragma unroll 4
    for (int i = seg; i < 512; i += G) {
      float4 c = tile[i];
      float d = (qq + c.w) - 2.f * ((qx*c.x + qy*c.y) + qz*c.z);
      int gi = t0 + i;
      if (d < a[3]) {
        bool c0 = d < a[0], c1 = d < a[1], c2 = d < a[2];
        a[3]  = c2 ? a[2]  : d;              id[3] = c2 ? id[2] : gi;
        a[2]  = c1 ? a[1]  : (c2 ? d  : a[2]); id[2] = c1 ? id[1] : (c2 ? gi : id[2]);
        a[1]  = c0 ? a[0]  : (c1 ? d  : a[1]); id[1] = c0 ? id[0] : (c1 ? gi : id[1]);
        if (c0) { a[0] = d; id[0] = gi; }
      }
    }
  }
#pragma unroll
  for (int s = G/2; s >= 1; s >>= 1) {
    float bd[4]; int bi[4];
#pragma unroll
    for (int j = 0; j < 4; ++j) { bd[j] = __shfl_xor(a[j], s); bi[j] = __shfl_xor(id[j], s); }
#pragma unroll
    for (int j = 0; j < 4; ++j) {
      float od = bd[3-j]; int ob = bi[3-j];
      bool take = (od < a[j]) || (od == a[j] && ob < id[j]);
      a[j]  = take ? od : a[j];
      id[j] = take ? ob : id[j];
    }
#pragma unroll
    for (int st = 2; st >= 1; st >>= 1) {
#pragma unroll
      for (int j = 0; j < 4; ++j) {
        if ((j & st) == 0) {
          const int j2 = j + st;
          bool sw = (a[j2] < a[j]) || (a[j2] == a[j] && id[j2] < id[j]);
          float lod = sw ? a[j2] : a[j];  int loi = sw ? id[j2] : id[j];
          float hid = sw ? a[j]  : a[j2]; int hii = sw ? id[j]  : id[j2];
          a[j] = lod; id[j] = loi; a[j2] = hid; id[j2] = hii;
        }
      }
    }
  }
  if (seg == 0) {
    float d0 = fmaxf(a[0], 0.f), d1 = fmaxf(a[1], 0.f), d2 = fmaxf(a[2], 0.f);
    float r0 = 1.f/(d0 + 1e-8f), r1 = 1.f/(d1 + 1e-8f), r2 = 1.f/(d2 + 1e-8f);
    float s = (r0 + r1) + r2;
    size_t o = ((size_t)b * Mq + q) * 3;
    oidx[o+0] = id[0]; oidx[o+1] = id[1]; oidx[o+2] = id[2];
    ow[o+0] = r0/s; ow[o+1] = r1/s; ow[o+2] = r2/s;
  }
}

// ------------------------------------------------------------------
// Edge-conv neighbor mean: hbar[p] = [mean_k x[n_k], mean_k (pos_p - pos_nk), mean_k |rel|^2]
__global__ void hbar_kernel(const float* __restrict__ x, const float* __restrict__ pos,
                            const int* __restrict__ idx, int Mlvl, int C, int B,
                            float* __restrict__ out)
{
  const int Ct = C + 4;
  const int tot = B * Mlvl * Ct;
  int e = blockIdx.x * 256 + threadIdx.x;
  if (e >= tot) return;
  const int c  = e % Ct;
  const int p  = e / Ct;
  const int b  = p / Mlvl;
  const int lm = p % Mlvl;
  const int* ip = idx + (size_t)p * 16;
  float s = 0.f;
  if (c < C) {
    const float* xb = x + (size_t)b * Mlvl * C;
#pragma unroll 4
    for (int k = 0; k < 16; ++k) s += xb[(size_t)ip[k] * C + c];
  } else if (c < C + 3) {
    const int dd = c - C;
    const float* pb = pos + (size_t)b * Mlvl * 3;
    const float pc = pb[lm*3 + dd];
#pragma unroll 4
    for (int k = 0; k < 16; ++k) s += pc - pb[ip[k]*3 + dd];
  } else {
    const float* pb = pos + (size_t)b * Mlvl * 3;
    const float px = pb[lm*3+0], py = pb[lm*3+1], pz = pb[lm*3+2];
#pragma unroll 4
    for (int k = 0; k < 16; ++k) {
      int n = ip[k];
      float dx = px - pb[n*3+0], dy = py - pb[n*3+1], dz = pz - pb[n*3+2];
      s += (dx*dx + dy*dy) + dz*dz;
    }
  }
  out[e] = s * 0.0625f;
}

// ------------------------------------------------------------------
__global__ void interp_kernel(const float* __restrict__ f, const int* __restrict__ nidx,
                              const float* __restrict__ nw, int Mq, int Msub, int C, int B,
                              float* __restrict__ out)
{
  const int tot = B * Mq * C;
  int e = blockIdx.x * 256 + threadIdx.x;
  if (e >= tot) return;
  const int c = e % C;
  const int p = e / C;
  const int b = p / Mq;
  const float* fb = f + (size_t)b * Msub * C;
  const int* ip   = nidx + (size_t)p * 3;
  const float* wp = nw   + (size_t)p * 3;
  out[e] = (wp[0] * fb[(size_t)ip[0]*C + c] + wp[1] * fb[(size_t)ip[1]*C + c])
         +  wp[2] * fb[(size_t)ip[2]*C + c];
}

// ------------------------------------------------------------------
__global__ void gather_kernel(const float* __restrict__ src, const int* __restrict__ idx,
                              int Mq, int Msrc, int C, int B, float* __restrict__ dst)
{
  const int tot = B * Mq * C;
  int e = blockIdx.x * 256 + threadIdx.x;
  if (e >= tot) return;
  const int c = e % C;
  const int p = e / C;
  const int b = p / Mq;
  dst[e] = src[((size_t)b * Msrc + idx[p]) * C + c];
}

// ------------------------------------------------------------------
// Fused GEMM: out[M,F] = act( A[M,Ka]@W1[Ka,F] + B2[M,Kb]@W2[Kb,F] + bias )
// 64x64 tile, BK=16, 256 threads, 4x4 micro-tile. M,F multiples of 64; K zero-padded.
__global__ __launch_bounds__(256) void gemm_kernel(const float* __restrict__ A, int Ka,
                                                   const float* __restrict__ B2, int Kb,
                                                   const float* __restrict__ W1,
                                                   const float* __restrict__ W2,
                                                   const float* __restrict__ bias,
                                                   float* __restrict__ out,
                                                   int M, int F, int act)
{
  __shared__ __align__(16) float As[16][64];
  __shared__ __align__(16) float Ws[16][64];
  const int tid  = threadIdx.x;
  const int row0 = blockIdx.x * 64;
  const int col0 = blockIdx.y * 64;
  const int tx = tid & 15, ty = tid >> 4;
  const int K = Ka + Kb;
  float acc[4][4] = {};
  for (int k0 = 0; k0 < K; k0 += 16) {
#pragma unroll
    for (int i = 0; i < 4; ++i) {
      int e = tid + i * 256;
      int m = e & 63, kk = e >> 6;
      int k = k0 + kk;
      float v = 0.f;
      if (k < Ka)     v = A [(size_t)(row0 + m) * Ka + k];
      else if (k < K) v = B2[(size_t)(row0 + m) * Kb + (k - Ka)];
      As[kk][m] = v;
      float wv = 0.f;
      if (k < Ka)     wv = W1[(size_t)k * F + col0 + m];
      else if (k < K) wv = W2[(size_t)(k - Ka) * F + col0 + m];
      Ws[kk][m] = wv;
    }
    __syncthreads();
#pragma unroll
    for (int kk = 0; kk < 16; ++kk) {
      const float4 a4 = *reinterpret_cast<const float4*>(&As[kk][ty * 4]);
      const float4 b4 = *reinterpret_cast<const float4*>(&Ws[kk][tx * 4]);
      const float av[4] = {a4.x, a4.y, a4.z, a4.w};
      const float bv[4] = {b4.x, b4.y, b4.z, b4.w};
#pragma unroll
      for (int i2 = 0; i2 < 4; ++i2)
#pragma unroll
        for (int j2 = 0; j2 < 4; ++j2)
          acc[i2][j2] = fmaf(av[i2], bv[j2], acc[i2][j2]);
    }
    __syncthreads();
  }
#pragma unroll
  for (int i2 = 0; i2 < 4; ++i2) {
    int r = row0 + ty * 4 + i2;
#pragma unroll
    for (int j2 = 0; j2 < 4; ++j2) {
      int cc = col0 + tx * 4 + j2;
      float v = acc[i2][j2];
      if (bias) v += bias[cc];
      if (act)  v = leakyf(v);
      out[(size_t)r * F + cc] = v;
    }
  }
}

// ------------------------------------------------------------------
extern "C" void kernel_launch(void* const* d_in, const int* in_sizes, int n_in,
                              void* d_out, int out_size, void* d_ws, size_t ws_size,
                              hipStream_t stream)
{
  (void)in_sizes; (void)n_in; (void)out_size; (void)ws_size;
  const float* x          = (const float*)d_in[0];   // [2,8192,4]
  const float* pos        = (const float*)d_in[1];   // [2,8192,3]
  const float* w_self0    = (const float*)d_in[2];   // [4,64]
  const float* w_edge0    = (const float*)d_in[3];   // [8,64]
  const float* w_self1    = (const float*)d_in[4];   // [64,128]
  const float* w_edge1    = (const float*)d_in[5];   // [68,128]
  const float* w_self2    = (const float*)d_in[6];   // [128,256]
  const float* w_edge2    = (const float*)d_in[7];   // [132,256]
  const float* w_up1      = (const float*)d_in[8];   // [384,128]
  const float* b_up1      = (const float*)d_in[9];   // [128]
  const float* w_upc1s    = (const float*)d_in[10];  // [128,128]
  const float* w_upc1e    = (const float*)d_in[11];  // [132,128]
  const float* w_up0      = (const float*)d_in[12];  // [192,64]
  const float* b_up0      = (const float*)d_in[13];  // [64]
  const float* w_upc0s    = (const float*)d_in[14];  // [64,64]
  const float* w_upc0e    = (const float*)d_in[15];  // [68,64]
  const float* w_out      = (const float*)d_in[16];  // [64,128]
  const float* b_out      = (const float*)d_in[17];  // [128]
  float* out = (float*)d_out;                        // [2,8192,128]

  char* ws = (char*)d_ws;
  size_t off = 0;
  auto alloc = [&](size_t nbytes) -> void* {
    off = (off + 255) & ~(size_t)255;
    void* p = ws + off;
    off += nbytes;
    return p;
  };
  int*    knn0   = (int*)   alloc((size_t)2*8192*16*4);
  int*    knn1   = (int*)   alloc((size_t)2*4096*16*4);
  int*    knn2   = (int*)   alloc((size_t)2*2048*16*4);
  int*    idx1   = (int*)   alloc((size_t)2*4096*4);
  int*    idx2   = (int*)   alloc((size_t)2*2048*4);
  float*  pos1   = (float*) alloc((size_t)2*4096*3*4);
  float*  pos2   = (float*) alloc((size_t)2*2048*3*4);
  float4* pp0    = (float4*)alloc((size_t)2*8192*16);
  float4* pp1    = (float4*)alloc((size_t)2*4096*16);
  float4* pp2    = (float4*)alloc((size_t)2*2048*16);
  float*  feat0  = (float*) alloc((size_t)2*8192*64*4);
  float*  feat0g = (float*) alloc((size_t)2*4096*64*4);
  float*  feat1  = (float*) alloc((size_t)2*4096*128*4);
  float*  feat1g = (float*) alloc((size_t)2*2048*128*4);
  float*  feat2  = (float*) alloc((size_t)2*2048*256*4);
  int*    nn1i   = (int*)   alloc((size_t)2*4096*3*4);
  float*  nn1w   = (float*) alloc((size_t)2*4096*3*4);
  int*    nn0i   = (int*)   alloc((size_t)2*8192*3*4);
  float*  nn0w   = (float*) alloc((size_t)2*8192*3*4);
  float*  interp = (float*) alloc((size_t)2*4096*256*4);  // reused for interp0 (same size)
  float*  hbar   = (float*) alloc((size_t)2*8192*68*4);   // max of all hbar stages
  float*  fupa   = (float*) alloc((size_t)2*4096*128*4);  // fup1a, later fup0a (same size)
  float*  fup1   = (float*) alloc((size_t)2*4096*128*4);
  float*  fout   = (float*) alloc((size_t)2*8192*64*4);

  // --- packed pos level 0 ---
  pack_kernel<<<64, 256, 0, stream>>>(pos, 2*8192, pp0);
  // --- level 0: knn + edge conv ---
  knn_kernel<16><<<dim3(512, 2), 256, 0, stream>>>(pp0, 8192, knn0);
  hbar_kernel<<<512, 256, 0, stream>>>(x, pos, knn0, 8192, 4, 2, hbar);
  gemm_kernel<<<dim3(256, 1), 256, 0, stream>>>(x, 4, hbar, 8, w_self0, w_edge0, nullptr,
                                                feat0, 16384, 64, 1);
  // --- FPS level 1 + downsample ---
  fps_kernel<8192, 4096><<<2, 512, 0, stream>>>(pos, idx1, pos1, pp1);
  gather_kernel<<<2048, 256, 0, stream>>>(feat0, idx1, 4096, 8192, 64, 2, feat0g);
  knn_kernel<16><<<dim3(256, 2), 256, 0, stream>>>(pp1, 4096, knn1);
  hbar_kernel<<<2176, 256, 0, stream>>>(feat0g, pos1, knn1, 4096, 64, 2, hbar);
  gemm_kernel<<<dim3(128, 2), 256, 0, stream>>>(feat0g, 64, hbar, 68, w_self1, w_edge1, nullptr,
                                                feat1, 8192, 128, 1);
  // --- FPS level 2 + downsample ---
  fps_kernel<4096, 2048><<<2, 512, 0, stream>>>(pos1, idx2, pos2, pp2);
  gather_kernel<<<2048, 256, 0, stream>>>(feat1, idx2, 2048, 4096, 128, 2, feat1g);
  knn_kernel<16><<<dim3(128, 2), 256, 0, stream>>>(pp2, 2048, knn2);
  hbar_kernel<<<2112, 256, 0, stream>>>(feat1g, pos2, knn2, 2048, 128, 2, hbar);
  gemm_kernel<<<dim3(64, 4), 256, 0, stream>>>(feat1g, 128, hbar, 132, w_self2, w_edge2, nullptr,
                                               feat2, 4096, 256, 1);
  // --- up level 1: interp(feat2)->pos1, concat feat1, linear, edge conv ---
  three_nn_kernel<16><<<dim3(256, 2), 256, 0, stream>>>(pp1, pp2, 4096, 2048, nn1i, nn1w);
  interp_kernel<<<8192, 256, 0, stream>>>(feat2, nn1i, nn1w, 4096, 2048, 256, 2, interp);
  gemm_kernel<<<dim3(128, 2), 256, 0, stream>>>(interp, 256, feat1, 128,
                                                w_up1, w_up1 + (size_t)256 * 128, b_up1,
                                                fupa, 8192, 128, 1);
  hbar_kernel<<<4224, 256, 0, stream>>>(fupa, pos1, knn1, 4096, 128, 2, hbar);
  gemm_kernel<<<dim3(128, 2), 256, 0, stream>>>(fupa, 128, hbar, 132, w_upc1s, w_upc1e, nullptr,
                                                fup1, 8192, 128, 1);
  // --- up level 0: interp(fup1)->pos0, concat feat0, linear, edge conv ---
  three_nn_kernel<16><<<dim3(512, 2), 256, 0, stream>>>(pp0, pp1, 8192, 4096, nn0i, nn0w);
  interp_kernel<<<8192, 256, 0, stream>>>(fup1, nn0i, nn0w, 8192, 4096, 128, 2, interp);
  gemm_kernel<<<dim3(256, 1), 256, 0, stream>>>(interp, 128, feat0, 64,
                                                w_up0, w_up0 + (size_t)128 * 64, b_up0,
                                                fupa, 16384, 64, 1);
  hbar_kernel<<<4352, 256, 0, stream>>>(fupa, pos, knn0, 8192, 64, 2, hbar);
  gemm_kernel<<<dim3(256, 1), 256, 0, stream>>>(fupa, 64, hbar, 68, w_upc0s, w_upc0e, nullptr,
                                                fout, 16384, 64, 1);
  // --- final projection ---
  gemm_kernel<<<dim3(256, 2), 256, 0, stream>>>(fout, 64, nullptr, 0, w_out, nullptr, b_out,
                                                out, 16384, 128, 0);
}